// Round 5
// baseline (1220.613 us; speedup 1.0000x reference)
//
#include <hip/hip_runtime.h>

// cRNN: B=512, T=2048, I=4, H=100, O=1
// h_t = tanh(W_ih x_t + W_hh h_{t-1});  out[b,t] = W_fc.h_t + b_fc
// ONE WAVE per chain: thread t owns rows t and t+64 (t<36). All of h is held
// in-wave (vh = h[0..63] by lane, vh2 = h[64..99] in lanes 0..35), broadcast
// via v_readlane only -> zero LDS / zero barriers in the serial path. Each
// readlane feeds 2 FMAs (both owned rows). Output projection amortized per
// 64-step chunk from an LDS history in transposed [j][65] layout
// (odd stride -> conflict-free b32 column reads).

#define BB 512
#define TT 2048
#define II 4
#define HH 100
#define CHUNK 64
#define HSTR (CHUNK + 1)      // 65: odd word stride
#define NCH (TT / CHUNK)

__device__ __forceinline__ float rlf(float v, int l) {
    return __int_as_float(__builtin_amdgcn_readlane(__float_as_int(v), l));
}

__global__ __launch_bounds__(64, 1) void crnn_kernel(
    const float* __restrict__ x,     // [B,T,I]
    const float* __restrict__ W_ih,  // [H,I]
    const float* __restrict__ W_hh,  // [H,H]
    const float* __restrict__ W_fc,  // [1,H]
    const float* __restrict__ b_fc,  // [1]
    float* __restrict__ out)         // [B,T]
{
    __shared__ float xs[TT * II];          // 32 KB staged input
    __shared__ float hh[HH * HSTR];        // 26 KB: h history, [j][step] layout

    const int t = threadIdx.x;             // lane 0..63
    const int b = blockIdx.x;
    const int rA = t;                      // first owned row
    const bool hasB = (t < HH - 64);       // t < 36
    const int rB = hasB ? (t + 64) : (HH - 1);

    // ---- stage x[b] into LDS (coalesced float4) ----
    const float4* xg = reinterpret_cast<const float4*>(x + (size_t)b * TT * II);
    float4* xl = reinterpret_cast<float4*>(xs);
#pragma unroll
    for (int i = 0; i < (TT * II / 4) / 64; ++i)
        xl[i * 64 + t] = xg[i * 64 + t];

    // ---- per-thread weights in registers (two rows) ----
    float4 wihA = reinterpret_cast<const float4*>(W_ih)[rA];
    float4 wihB = reinterpret_cast<const float4*>(W_ih)[rB];
    float wrA[HH], wrB[HH];
    {
        const float4* ra = reinterpret_cast<const float4*>(W_hh + rA * HH);
        const float4* rb = reinterpret_cast<const float4*>(W_hh + rB * HH);
#pragma unroll
        for (int k4 = 0; k4 < HH / 4; ++k4) {
            float4 va = ra[k4], vb = rb[k4];
            wrA[4*k4+0] = va.x; wrA[4*k4+1] = va.y; wrA[4*k4+2] = va.z; wrA[4*k4+3] = va.w;
            wrB[4*k4+0] = vb.x; wrB[4*k4+1] = vb.y; wrB[4*k4+2] = vb.z; wrB[4*k4+3] = vb.w;
        }
    }
    const float wfcA = W_fc[rA];                       // lane t holds wfc[t]
    const float wfcB = hasB ? W_fc[t + 64] : 0.f;      // lanes 0..35: wfc[64..99]
    const float bias = b_fc[0];
    __syncthreads();

    float vh  = 0.f;                       // h[t]
    float vh2 = 0.f;                       // h[t+64] (lanes 0..35)
    float* outb = out + (size_t)b * TT;
    const float4* xs4 = reinterpret_cast<const float4*>(xs);
    float* hwA = hh + rA * HSTR;           // history write ptrs (bank-clean)
    float* hwB = hh + (t + 64) * HSTR;     // only used when hasB

    for (int c = 0; c < NCH; ++c) {
        for (int s = 0; s < CHUNK; ++s) {
            float4 xv = xs4[c * CHUNK + s];            // broadcast LDS read
            float a0 = wihA.x * xv.x, a1 = wihA.y * xv.y;
            float a2 = wihA.z * xv.z, a3 = wihA.w * xv.w;
            float b0 = wihB.x * xv.x, b1 = wihB.y * xv.y;
            float b2 = wihB.z * xv.z, b3 = wihB.w * xv.w;
#pragma unroll
            for (int k = 0; k < 64; k += 4) {          // h[0..63] from vh
                float h0 = rlf(vh, k + 0), h1 = rlf(vh, k + 1);
                float h2 = rlf(vh, k + 2), h3 = rlf(vh, k + 3);
                a0 = fmaf(wrA[k+0], h0, a0);  b0 = fmaf(wrB[k+0], h0, b0);
                a1 = fmaf(wrA[k+1], h1, a1);  b1 = fmaf(wrB[k+1], h1, b1);
                a2 = fmaf(wrA[k+2], h2, a2);  b2 = fmaf(wrB[k+2], h2, b2);
                a3 = fmaf(wrA[k+3], h3, a3);  b3 = fmaf(wrB[k+3], h3, b3);
            }
#pragma unroll
            for (int k = 64; k < HH; k += 4) {         // h[64..99] from vh2
                float h0 = rlf(vh2, k - 64 + 0), h1 = rlf(vh2, k - 64 + 1);
                float h2 = rlf(vh2, k - 64 + 2), h3 = rlf(vh2, k - 64 + 3);
                a0 = fmaf(wrA[k+0], h0, a0);  b0 = fmaf(wrB[k+0], h0, b0);
                a1 = fmaf(wrA[k+1], h1, a1);  b1 = fmaf(wrB[k+1], h1, b1);
                a2 = fmaf(wrA[k+2], h2, a2);  b2 = fmaf(wrB[k+2], h2, b2);
                a3 = fmaf(wrA[k+3], h3, a3);  b3 = fmaf(wrB[k+3], h3, b3);
            }
            float accA = (a0 + a1) + (a2 + a3);
            float accB = (b0 + b1) + (b2 + b3);
            // tanh(a) = 1 - 2/(exp(2a)+1)
            float eA = __expf(2.f * accA);
            float eB = __expf(2.f * accB);
            float hnA = 1.f - 2.f * __builtin_amdgcn_rcpf(eA + 1.f);
            float hnB = 1.f - 2.f * __builtin_amdgcn_rcpf(eB + 1.f);
            vh = hnA;
            vh2 = hnB;
            hwA[s] = hnA;                              // bank = (t + s) % 32: clean
            if (hasB) hwB[s] = hnB;
        }
        __syncthreads();                               // single-wave: near-free

        // ---- amortized output projection: lane t -> out[c*64 + t] ----
        const float* hcol = hh + t;                    // reads hh[j*65 + t]
        float csum = 0.f;
#pragma unroll
        for (int j = 0; j < 64; ++j)
            csum = fmaf(rlf(wfcA, j), hcol[j * HSTR], csum);
#pragma unroll
        for (int j = 64; j < HH; ++j)
            csum = fmaf(rlf(wfcB, j - 64), hcol[j * HSTR], csum);
        outb[c * CHUNK + t] = csum + bias;
        __syncthreads();                               // before hh reuse
    }
}

extern "C" void kernel_launch(void* const* d_in, const int* in_sizes, int n_in,
                              void* d_out, int out_size, void* d_ws, size_t ws_size,
                              hipStream_t stream) {
    const float* x    = (const float*)d_in[0];
    const float* W_ih = (const float*)d_in[1];
    const float* W_hh = (const float*)d_in[2];
    const float* W_fc = (const float*)d_in[3];
    const float* b_fc = (const float*)d_in[4];
    float* out = (float*)d_out;
    crnn_kernel<<<BB, 64, 0, stream>>>(x, W_ih, W_hh, W_fc, b_fc, out);
}

// Round 6
// 1109.879 us; speedup vs baseline: 1.0998x; 1.0998x over previous
//
#include <hip/hip_runtime.h>

// cRNN: B=512, T=2048, I=4, H=100, O=1
// h_t = tanh(W_ih x_t + W_hh h_{t-1});  out[b,t] = W_fc.h_t + b_fc
// One block (128 thr, 2 waves) per chain; thread j owns row j (132 VGPR shape
// that is known to allocate). Per step: readlane-broadcast h with an 8-deep
// software pipeline (rl -> consumer distance >= 8 to absorb SGPR hazards);
// the barrier + partner-half LDS read are hoisted into the MIDDLE of the
// own-half FMA stream so the LDS latency and barrier hide under register work.
// Output projection amortized over a 64-step LDS history per chunk.

#define BB 512
#define TT 2048
#define II 4
#define HH 100
#define HP 108              // history row stride in words (16B-aligned, pads zeroed)
#define CHUNK 64
#define NCH (TT / CHUNK)

__device__ __forceinline__ float rlf(float v, int l) {
    return __int_as_float(__builtin_amdgcn_readlane(__float_as_int(v), l));
}

// prefetch 8 h values (readlane) into named regs B0..B7
#define PF8(B, SRC, L) \
    B##0 = rlf(SRC, (L)+0); B##1 = rlf(SRC, (L)+1); B##2 = rlf(SRC, (L)+2); B##3 = rlf(SRC, (L)+3); \
    B##4 = rlf(SRC, (L)+4); B##5 = rlf(SRC, (L)+5); B##6 = rlf(SRC, (L)+6); B##7 = rlf(SRC, (L)+7);
#define PF4(B, SRC, L) \
    B##0 = rlf(SRC, (L)+0); B##1 = rlf(SRC, (L)+1); B##2 = rlf(SRC, (L)+2); B##3 = rlf(SRC, (L)+3);
// consume 8 prefetched h values against weights wr[K..K+7]
#define FM8(B, K) \
    a0 = fmaf(wr[(K)+0], B##0, a0); a1 = fmaf(wr[(K)+1], B##1, a1); \
    a2 = fmaf(wr[(K)+2], B##2, a2); a3 = fmaf(wr[(K)+3], B##3, a3); \
    a0 = fmaf(wr[(K)+4], B##4, a0); a1 = fmaf(wr[(K)+5], B##5, a1); \
    a2 = fmaf(wr[(K)+6], B##6, a2); a3 = fmaf(wr[(K)+7], B##7, a3);
#define FM4(B, K) \
    a0 = fmaf(wr[(K)+0], B##0, a0); a1 = fmaf(wr[(K)+1], B##1, a1); \
    a2 = fmaf(wr[(K)+2], B##2, a2); a3 = fmaf(wr[(K)+3], B##3, a3);

__global__ __launch_bounds__(128, 1) void crnn_kernel(
    const float* __restrict__ x,     // [B,T,I]
    const float* __restrict__ W_ih,  // [H,I]
    const float* __restrict__ W_hh,  // [H,H]
    const float* __restrict__ W_fc,  // [1,H]
    const float* __restrict__ b_fc,  // [1]
    float* __restrict__ out)         // [B,T]
{
    __shared__ float xs[TT * II];          // 32 KB staged input
    __shared__ float hh[CHUNK * HP];       // 27 KB h history (row s = h after step s)
    __shared__ float wfcs[HP];
    __shared__ float pt[2][CHUNK];

    const int tid  = threadIdx.x;
    const int b    = blockIdx.x;
    const int lane = tid & 63;
    const int w    = tid >> 6;
    const int j    = tid;                  // owned row / output index
    const int jj   = (j < HH) ? j : HH - 1;
    const bool act = (j < HH);

    // ---- stage x[b] into LDS (coalesced float4) ----
    const float4* xg = reinterpret_cast<const float4*>(x + (size_t)b * TT * II);
    float4* xl = reinterpret_cast<float4*>(xs);
#pragma unroll
    for (int it = 0; it < (TT * II / 4) / 128; ++it)
        xl[it * 128 + tid] = xg[it * 128 + tid];

    // ---- per-thread weights in registers ----
    float4 wih = reinterpret_cast<const float4*>(W_ih)[jj];
    float wr[HH];
    const float4* wrow = reinterpret_cast<const float4*>(W_hh + jj * HH);
#pragma unroll
    for (int k4 = 0; k4 < HH / 4; ++k4) {
        float4 v = wrow[k4];
        wr[4 * k4 + 0] = v.x; wr[4 * k4 + 1] = v.y;
        wr[4 * k4 + 2] = v.z; wr[4 * k4 + 3] = v.w;
    }
    if (tid < HP) wfcs[tid] = (tid < HH) ? W_fc[tid] : 0.f;
    const float bias = b_fc[0];
    for (int i = tid; i < CHUNK * HP; i += 128) hh[i] = 0.f;  // h "row -1" + pads
    __syncthreads();

    // partner-half read offset within a history row:
    // W0 fetches h[64..99] (lanes 0..35), W1 fetches h[0..63]
    const int voff = w ? lane : (64 + (lane < 36 ? lane : 35));

    float vh = 0.f;                        // own h value (h_0 = 0)
    float* outb = out + (size_t)b * TT;

    for (int c = 0; c < NCH; ++c) {
        const float4* xs4 = reinterpret_cast<const float4*>(xs) + c * CHUNK;
#pragma unroll 1
        for (int s = 0; s < CHUNK; ++s) {
            const float* rowPrev = hh + (((s + CHUNK - 1) & (CHUNK - 1)) * HP);
            float4 xv = xs4[s];
            float a0 = wih.x * xv.x;
            float a1 = wih.y * xv.y;
            float a2 = wih.z * xv.z;
            float a3 = wih.w * xv.w;
            float p0,p1,p2,p3,p4,p5,p6,p7;
            float q0,q1,q2,q3,q4,q5,q6,q7;
            float vo;

            // ---- section 1: own-half head (no barrier needed: vh is a reg) ----
            if (w == 0) {
                PF8(p, vh, 0)
                PF8(q, vh, 8)   FM8(p, 0)
                PF8(p, vh, 16)  FM8(q, 8)
                PF8(q, vh, 24)  FM8(p, 16)
                // exit: q = k24..31 pending, next fetch k32
            } else {
                PF8(p, vh, 0)                 // k64..71
                PF8(q, vh, 8)   FM8(p, 64)
                // exit: q = k72..79 pending
            }

            // ---- mid-step barrier: partner's h row (step s-1) now visible ----
            __syncthreads();
            vo = rowPrev[voff];              // latency hidden under section 2 head

            // ---- section 2: rest of own half, then partner half via vo ----
            if (w == 0) {
                PF8(p, vh, 32)  FM8(q, 24)
                PF8(q, vh, 40)  FM8(p, 32)
                PF8(p, vh, 48)  FM8(q, 40)
                PF8(q, vh, 56)  FM8(p, 48)
                PF8(p, vo, 0)   FM8(q, 56)   // vo first consumed ~4 groups after read
                PF8(q, vo, 8)   FM8(p, 64)
                PF8(p, vo, 16)  FM8(q, 72)
                PF8(q, vo, 24)  FM8(p, 80)
                PF4(p, vo, 32)  FM8(q, 88)
                FM4(p, 96)
            } else {
                PF8(p, vh, 16)  FM8(q, 72)
                PF8(q, vh, 24)  FM8(p, 80)
                PF4(p, vh, 32)  FM8(q, 88)   // p0..3 = k96..99
                PF8(q, vo, 0)   FM4(p, 96)
                PF8(p, vo, 8)   FM8(q, 0)
                PF8(q, vo, 16)  FM8(p, 8)
                PF8(p, vo, 24)  FM8(q, 16)
                PF8(q, vo, 32)  FM8(p, 24)
                PF8(p, vo, 40)  FM8(q, 32)
                PF8(q, vo, 48)  FM8(p, 40)
                PF8(p, vo, 56)  FM8(q, 48)
                FM8(p, 56)
            }

            float acc = (a0 + a1) + (a2 + a3);
            float e   = __expf(2.f * acc);             // tanh = 1 - 2/(e^{2a}+1)
            float hn  = 1.f - 2.f * __builtin_amdgcn_rcpf(e + 1.f);
            vh = hn;
            if (act) hh[s * HP + j] = hn;              // history + partner exchange
        }

        // ---- amortized output projection over the 64-row history ----
        __syncthreads();                               // all step-63 writes visible
        const int tl = tid & (CHUNK - 1);
        const int kh = tid >> 6;
        const int k0 = kh * 52;                        // halves 0..51 / 52..103 (pads 0)
        const float4* wf4 = reinterpret_cast<const float4*>(wfcs + k0);
        const float4* hr  = reinterpret_cast<const float4*>(hh + tl * HP + k0);
        float csum = 0.f;
#pragma unroll
        for (int i = 0; i < 13; ++i) {
            float4 hvv = hr[i];
            float4 wv  = wf4[i];
            csum = fmaf(hvv.x, wv.x, csum);
            csum = fmaf(hvv.y, wv.y, csum);
            csum = fmaf(hvv.z, wv.z, csum);
            csum = fmaf(hvv.w, wv.w, csum);
        }
        pt[kh][tl] = csum;
        __syncthreads();
        if (tid < CHUNK) outb[c * CHUNK + tid] = (pt[0][tid] + pt[1][tid]) + bias;
    }
}

extern "C" void kernel_launch(void* const* d_in, const int* in_sizes, int n_in,
                              void* d_out, int out_size, void* d_ws, size_t ws_size,
                              hipStream_t stream) {
    const float* x    = (const float*)d_in[0];
    const float* W_ih = (const float*)d_in[1];
    const float* W_hh = (const float*)d_in[2];
    const float* W_fc = (const float*)d_in[3];
    const float* b_fc = (const float*)d_in[4];
    float* out = (float*)d_out;
    crnn_kernel<<<BB, 128, 0, stream>>>(x, W_ih, W_hh, W_fc, b_fc, out);
}

// Round 8
// 1030.602 us; speedup vs baseline: 1.1844x; 1.0769x over previous
//
#include <hip/hip_runtime.h>

// cRNN: B=512, T=2048, I=4, H=100, O=1
// h_t = tanh(W_ih x_t + W_hh h_{t-1});  out[b,t] = W_fc.h_t + b_fc
// One block (128 thr, 2 waves) per chain. K-SPLIT: wave w owns k in
// [w*50, w*50+50); each lane owns TWO output rows (j=lane, j=lane+64) so
// every readlane feeds TWO fmas (halves the readlane count, the round-4
// bottleneck). Per step each wave makes partial sums for both rows, the
// waves swap partials via one float2 LDS write/read + 1 barrier, and BOTH
// waves compute all tanhs so each holds the full h in registers (vh, vh2)
// -> no h broadcast. Output projection amortized over a 64-step history.
// Round-8 fix: wave 0's k-loop tail (KH=50 not divisible by 4) no longer
// reads wA[50..51] OOB.

#define BB 512
#define TT 2048
#define II 4
#define HH 100
#define KH 50               // k-half per wave
#define HP 108              // history row stride (16B-aligned, pads zeroed)
#define CHUNK 64
#define NCH (TT / CHUNK)

__device__ __forceinline__ float rlf(float v, int l) {
    return __int_as_float(__builtin_amdgcn_readlane(__float_as_int(v), l));
}

__global__ __launch_bounds__(128, 1) void crnn_kernel(
    const float* __restrict__ x,     // [B,T,I]
    const float* __restrict__ W_ih,  // [H,I]
    const float* __restrict__ W_hh,  // [H,H]
    const float* __restrict__ W_fc,  // [1,H]
    const float* __restrict__ b_fc,  // [1]
    float* __restrict__ out)         // [B,T]
{
    __shared__ float  xs[TT * II];         // 32 KB staged input
    __shared__ float  hh[CHUNK * HP];      // 27 KB h history
    __shared__ float  wfcs[HP];
    __shared__ float2 pw[2][2][64];        // [step parity][wave][lane] partials
    __shared__ float  pt[2][CHUNK];

    const int tid  = threadIdx.x;
    const int b    = blockIdx.x;
    const int lane = tid & 63;
    const int w    = tid >> 6;
    const int rA   = lane;                         // first owned row
    const int rB   = (lane < HH - 64) ? (64 + lane) : (HH - 1);  // clamp

    // ---- stage x[b] into LDS (coalesced float4) ----
    const float4* xg = reinterpret_cast<const float4*>(x + (size_t)b * TT * II);
    float4* xl = reinterpret_cast<float4*>(xs);
#pragma unroll
    for (int it = 0; it < (TT * II / 4) / 128; ++it)
        xl[it * 128 + tid] = xg[it * 128 + tid];

    // ---- per-thread weights: rows rA,rB restricted to this wave's k-half ----
    float wA[KH], wB[KH];
    {
        const float2* pa = reinterpret_cast<const float2*>(W_hh + rA * HH + w * KH);
        const float2* pb = reinterpret_cast<const float2*>(W_hh + rB * HH + w * KH);
#pragma unroll
        for (int i = 0; i < KH / 2; ++i) {
            float2 va = pa[i], vb = pb[i];
            wA[2 * i] = va.x; wA[2 * i + 1] = va.y;
            wB[2 * i] = vb.x; wB[2 * i + 1] = vb.y;
        }
    }
    float4 wihA = reinterpret_cast<const float4*>(W_ih)[rA];
    float4 wihB = reinterpret_cast<const float4*>(W_ih)[rB];
    if (tid < HP) wfcs[tid] = (tid < HH) ? W_fc[tid] : 0.f;
    const float bias = b_fc[0];
    // zero history pad columns (HH..HP-1) once (epilogue float4 reads them)
    for (int i = tid; i < CHUNK * (HP - HH); i += 128) {
        int r = i / (HP - HH), p = i % (HP - HH);
        hh[r * HP + HH + p] = 0.f;
    }
    __syncthreads();

    float vh  = 0.f;                       // h[lane]      (full h in-wave)
    float vh2 = 0.f;                       // h[lane+64]   (lanes 0..35 valid)
    float* outb = out + (size_t)b * TT;
    const float4* xs4 = reinterpret_cast<const float4*>(xs);

    for (int c = 0; c < NCH; ++c) {
#pragma unroll 1
        for (int s = 0; s < CHUNK; ++s) {
            float a0 = 0.f, a1 = 0.f, a2 = 0.f, a3 = 0.f;
            float b0 = 0.f, b1 = 0.f, b2 = 0.f, b3 = 0.f;

            if (w == 0) {
                // wave 0: xp contribution + k = 0..49 (all from vh)
                float4 xv = xs4[c * CHUNK + s];
                a0 = wihA.x * xv.x; a1 = wihA.y * xv.y;
                a2 = wihA.z * xv.z; a3 = wihA.w * xv.w;
                b0 = wihB.x * xv.x; b1 = wihB.y * xv.y;
                b2 = wihB.z * xv.z; b3 = wihB.w * xv.w;
#pragma unroll
                for (int i = 0; i < 48; i += 4) {          // k = 0..47
                    float h0 = rlf(vh, i + 0), h1 = rlf(vh, i + 1);
                    float h2 = rlf(vh, i + 2), h3 = rlf(vh, i + 3);
                    a0 = fmaf(wA[i + 0], h0, a0);  b0 = fmaf(wB[i + 0], h0, b0);
                    a1 = fmaf(wA[i + 1], h1, a1);  b1 = fmaf(wB[i + 1], h1, b1);
                    a2 = fmaf(wA[i + 2], h2, a2);  b2 = fmaf(wB[i + 2], h2, b2);
                    a3 = fmaf(wA[i + 3], h3, a3);  b3 = fmaf(wB[i + 3], h3, b3);
                }
                {   // tail: k = 48, 49 (KH=50 not divisible by 4)
                    float h0 = rlf(vh, 48), h1 = rlf(vh, 49);
                    a0 = fmaf(wA[48], h0, a0);  b0 = fmaf(wB[48], h0, b0);
                    a1 = fmaf(wA[49], h1, a1);  b1 = fmaf(wB[49], h1, b1);
                }
            } else {
                // wave 1: k = 50..63 from vh, k = 64..99 from vh2
#pragma unroll
                for (int i = 0; i < 12; i += 4) {          // k = 50..61
                    float h0 = rlf(vh, 50 + i), h1 = rlf(vh, 51 + i);
                    float h2 = rlf(vh, 52 + i), h3 = rlf(vh, 53 + i);
                    a0 = fmaf(wA[i + 0], h0, a0);  b0 = fmaf(wB[i + 0], h0, b0);
                    a1 = fmaf(wA[i + 1], h1, a1);  b1 = fmaf(wB[i + 1], h1, b1);
                    a2 = fmaf(wA[i + 2], h2, a2);  b2 = fmaf(wB[i + 2], h2, b2);
                    a3 = fmaf(wA[i + 3], h3, a3);  b3 = fmaf(wB[i + 3], h3, b3);
                }
                {   // i = 12,13 -> k = 62,63
                    float h0 = rlf(vh, 62), h1 = rlf(vh, 63);
                    a0 = fmaf(wA[12], h0, a0);  b0 = fmaf(wB[12], h0, b0);
                    a1 = fmaf(wA[13], h1, a1);  b1 = fmaf(wB[13], h1, b1);
                }
#pragma unroll
                for (int i = 14; i < 46; i += 4) {   // k = 64..95
                    float h0 = rlf(vh2, i - 14), h1 = rlf(vh2, i - 13);
                    float h2 = rlf(vh2, i - 12), h3 = rlf(vh2, i - 11);
                    a0 = fmaf(wA[i + 0], h0, a0);  b0 = fmaf(wB[i + 0], h0, b0);
                    a1 = fmaf(wA[i + 1], h1, a1);  b1 = fmaf(wB[i + 1], h1, b1);
                    a2 = fmaf(wA[i + 2], h2, a2);  b2 = fmaf(wB[i + 2], h2, b2);
                    a3 = fmaf(wA[i + 3], h3, a3);  b3 = fmaf(wB[i + 3], h3, b3);
                }
                {   // i = 46..49 -> k = 96..99 (vh2 lanes 32..35)
                    float h0 = rlf(vh2, 32), h1 = rlf(vh2, 33);
                    float h2 = rlf(vh2, 34), h3 = rlf(vh2, 35);
                    a0 = fmaf(wA[46], h0, a0);  b0 = fmaf(wB[46], h0, b0);
                    a1 = fmaf(wA[47], h1, a1);  b1 = fmaf(wB[47], h1, b1);
                    a2 = fmaf(wA[48], h2, a2);  b2 = fmaf(wB[48], h2, b2);
                    a3 = fmaf(wA[49], h3, a3);  b3 = fmaf(wB[49], h3, b3);
                }
            }

            float accA = (a0 + a1) + (a2 + a3);
            float accB = (b0 + b1) + (b2 + b3);

            // ---- partial exchange (parity-double-buffered, 1 barrier) ----
            pw[s & 1][w][lane] = make_float2(accA, accB);
            __syncthreads();
            float2 po = pw[s & 1][w ^ 1][lane];
            float sA = accA + po.x;
            float sB = accB + po.y;

            // both waves compute both tanhs -> full h stays in-wave
            float eA = __expf(2.f * sA);
            float eB = __expf(2.f * sB);
            vh  = 1.f - 2.f * __builtin_amdgcn_rcpf(eA + 1.f);
            vh2 = 1.f - 2.f * __builtin_amdgcn_rcpf(eB + 1.f);

            if (w == 0) {                          // history for the epilogue
                hh[s * HP + lane] = vh;
                if (lane < HH - 64) hh[s * HP + 64 + lane] = vh2;
            }
        }

        // ---- amortized output projection over the 64-row history ----
        __syncthreads();                           // history writes visible
        const int tl = tid & (CHUNK - 1);
        const int kh = tid >> 6;
        const int k0 = kh * 52;                    // halves 0..51 / 52..103 (pads 0)
        const float4* wf4 = reinterpret_cast<const float4*>(wfcs + k0);
        const float4* hr  = reinterpret_cast<const float4*>(hh + tl * HP + k0);
        float csum = 0.f;
#pragma unroll
        for (int i = 0; i < 13; ++i) {
            float4 hvv = hr[i];
            float4 wv  = wf4[i];
            csum = fmaf(hvv.x, wv.x, csum);
            csum = fmaf(hvv.y, wv.y, csum);
            csum = fmaf(hvv.z, wv.z, csum);
            csum = fmaf(hvv.w, wv.w, csum);
        }
        pt[kh][tl] = csum;
        __syncthreads();
        if (tid < CHUNK) outb[c * CHUNK + tid] = (pt[0][tid] + pt[1][tid]) + bias;
    }
}

extern "C" void kernel_launch(void* const* d_in, const int* in_sizes, int n_in,
                              void* d_out, int out_size, void* d_ws, size_t ws_size,
                              hipStream_t stream) {
    const float* x    = (const float*)d_in[0];
    const float* W_ih = (const float*)d_in[1];
    const float* W_hh = (const float*)d_in[2];
    const float* W_fc = (const float*)d_in[3];
    const float* b_fc = (const float*)d_in[4];
    float* out = (float*)d_out;
    crnn_kernel<<<BB, 128, 0, stream>>>(x, W_ih, W_hh, W_fc, b_fc, out);
}